// Round 10
// baseline (461.439 us; speedup 1.0000x reference)
//
#include <hip/hip_runtime.h>
#include <hip/hip_bf16.h>

#define NN 100000
#define EE 1600000

constexpr int SCAN_BLK = 1024;                       // elements per scan block (256 thr * 4)
constexpr int NB_SCAN  = (NN + SCAN_BLK - 1) / SCAN_BLK;  // 98

// Range-partitioned scatter: 8 dst-ranges
constexpr int NR  = 8;
constexpr int RS  = NN / NR;        // 12500 nodes per range
constexpr int CB  = 200;            // edge chunks
constexpr int CE  = EE / CB;        // 8000 edges per chunk (exact)
constexpr int RPL = 8;              // histogram replicas (cuts same-address atomic depth 8x)
constexpr int HB  = 2048;           // edges per hist block

// ---------------- CSR build ----------------

__global__ void zero_int(int* __restrict__ p, int n) {
    int i = blockIdx.x * 256 + threadIdx.x;
    if (i < n) p[i] = 0;
}

// Phase A: replica histogram + rank. Block b uses replica b&7; 8-deep batch of
// independent atomic-with-returns; rank written back coalesced.
__global__ __launch_bounds__(256) void hist_rank_k(const int* __restrict__ ei,
                                                   int* __restrict__ degR,
                                                   int* __restrict__ rank) {
    int base = blockIdx.x * HB;
    int* __restrict__ deg = degR + (size_t)(blockIdx.x & (RPL - 1)) * NN;
    const int* __restrict__ dstp = ei + EE;
    int tid = threadIdx.x;
    int d[8], s[8], r[8];
    #pragma unroll
    for (int k = 0; k < 8; ++k) {
        int off = base + tid + k * 256;
        bool v = off < EE;
        d[k] = v ? dstp[off] : -1;
        s[k] = v ? ei[off]   : -1;
        r[k] = 0;
    }
    #pragma unroll
    for (int k = 0; k < 8; ++k) {
        if (d[k] >= 0 && s[k] != d[k]) r[k] = atomicAdd(&deg[d[k]], 1);
    }
    #pragma unroll
    for (int k = 0; k < 8; ++k) {
        int off = base + tid + k * 256;
        if (off < EE) rank[off] = r[k];
    }
}

// Per-node replica prefix: degR[r][d] -> exclusive prefix over replicas; deg[d] = total.
__global__ void combine_k(int* __restrict__ degR, int* __restrict__ deg) {
    int d = blockIdx.x * 256 + threadIdx.x;
    if (d < NN) {
        int run = 0;
        #pragma unroll
        for (int r = 0; r < RPL; ++r) {
            int v = degR[(size_t)r * NN + d];
            degR[(size_t)r * NN + d] = run;
            run += v;
        }
        deg[d] = run;
    }
}

__global__ void sum_blocks(const int* __restrict__ deg, int* __restrict__ partials) {
    __shared__ int sh[256];
    int t = threadIdx.x;
    int base = blockIdx.x * SCAN_BLK + t * 4;
    int s = 0;
    #pragma unroll
    for (int k = 0; k < 4; ++k) { int i = base + k; if (i < NN) s += deg[i]; }
    sh[t] = s; __syncthreads();
    for (int off = 128; off > 0; off >>= 1) {
        if (t < off) sh[t] += sh[t + off];
        __syncthreads();
    }
    if (t == 0) partials[blockIdx.x] = sh[0];
}

__global__ void scan_partials(int* __restrict__ partials) {
    __shared__ int sh[128];
    int t = threadIdx.x;
    int v = (t < NB_SCAN) ? partials[t] : 0;
    sh[t] = v;
    __syncthreads();
    for (int off = 1; off < 128; off <<= 1) {
        int tmp = (t >= off) ? sh[t - off] : 0;
        __syncthreads();
        sh[t] += tmp;
        __syncthreads();
    }
    if (t < NB_SCAN) partials[t] = sh[t] - v;   // exclusive prefix
}

// Writes rowptr AND adds the node's global base into all replica offsets,
// making degR[r][d] an absolute col index base.
__global__ void scan_final(const int* __restrict__ deg, const int* __restrict__ partials,
                           int* __restrict__ rowptr, int* __restrict__ degR) {
    __shared__ int sh[256];
    int t = threadIdx.x;
    int base = blockIdx.x * SCAN_BLK + t * 4;
    int v[4]; int s = 0;
    #pragma unroll
    for (int k = 0; k < 4; ++k) { int i = base + k; v[k] = (i < NN) ? deg[i] : 0; s += v[k]; }
    sh[t] = s; __syncthreads();
    for (int off = 1; off < 256; off <<= 1) {
        int tmp = (t >= off) ? sh[t - off] : 0;
        __syncthreads();
        sh[t] += tmp;
        __syncthreads();
    }
    int pref = partials[blockIdx.x] + sh[t] - s;
    #pragma unroll
    for (int k = 0; k < 4; ++k) {
        int i = base + k;
        if (i < NN) {
            rowptr[i] = pref;
            #pragma unroll
            for (int r = 0; r < RPL; ++r) degR[(size_t)r * NN + i] += pref;
            pref += v[k];
            if (i == NN - 1) rowptr[NN] = pref;
        }
    }
}

// Phase C: no atomics. p = degR[rep][d] + rank[e] (one random L2/L3 read),
// col[p] = s. Range partitioning keeps writes in a small slice; 8-deep batch.
__global__ __launch_bounds__(256) void scatter2_k(const int* __restrict__ ei,
                                                  const int* __restrict__ rank,
                                                  const int* __restrict__ degR,
                                                  int* __restrict__ col) {
    int rg = blockIdx.x % NR, chunk = blockIdx.x / NR;
    int lo = rg * RS, hi = lo + RS;
    const int* __restrict__ dstp = ei + EE;
    int base = chunk * CE;
    int tid = threadIdx.x;
    for (int ii = 0; ii < CE; ii += 2048) {
        int d[8], s[8], rk[8], ix[8];
        #pragma unroll
        for (int k = 0; k < 8; ++k) {
            int off = ii + tid + k * 256;
            int i = base + off;
            bool v = off < CE;
            ix[k] = i;
            d[k]  = v ? dstp[i] : -1;
            s[k]  = v ? ei[i]   : -1;
            rk[k] = v ? rank[i] : 0;
        }
        int p[8]; bool keep[8];
        #pragma unroll
        for (int k = 0; k < 8; ++k) {
            keep[k] = (d[k] >= lo && d[k] < hi && s[k] != d[k]);
            if (keep[k]) {
                int rep = (ix[k] / HB) & (RPL - 1);     // hist block replica of edge
                p[k] = degR[(size_t)rep * NN + d[k]] + rk[k];
            }
        }
        #pragma unroll
        for (int k = 0; k < 8; ++k) {
            if (keep[k]) col[p[k]] = s[k];
        }
    }
}

// ---------------- GEMM (h = x @ W) + per-node record ----------------
// Register-blocked 4x4 per thread. Epilogue writes an interleaved per-node
// record into Rb (stride RSU uints): [0..H) = ssrc (f32), [8..8+M/2) = h (bf16
// packed 2/uint). sdst stays a separate f32 array (only read for own node).

template<int K, int M, int H, int NPB, int RSU>
__global__ __launch_bounds__(256) void gemm_tile(const float* __restrict__ xin,
                          const float* __restrict__ W,
                          const float* __restrict__ att,
                          unsigned* __restrict__ Rb,
                          float* __restrict__ sdst) {
    constexpr int C   = M / H;
    constexpr int MG  = M / 4;               // col-groups (4 cols per thread)
    constexpr int NG  = NPB / 4;
    static_assert(MG * NG == 256, "tile mismatch");
    constexpr int K4  = K / 4;
    constexpr int KC4 = (K4 > 16) ? 16 : K4;
    constexpr int NCH = K4 / KC4;

    __shared__ float4 Wq[K * MG];
    __shared__ float4 Xq[NPB * KC4];

    int tid = threadIdx.x;
    const float4* W4 = (const float4*)W;
    for (int i = tid; i < K * MG; i += 256) Wq[i] = W4[i];

    int node0 = blockIdx.x * NPB;
    const float4* x4 = (const float4*)xin;

    int mg = tid % MG, ng = tid / MG;
    int nb = ng * 4;
    float acc[4][4];
    #pragma unroll
    for (int i = 0; i < 4; ++i)
        #pragma unroll
        for (int j = 0; j < 4; ++j) acc[i][j] = 0.f;

    for (int ch = 0; ch < NCH; ++ch) {
        __syncthreads();
        for (int i = tid; i < NPB * KC4; i += 256) {
            int n = i / KC4, k4l = i % KC4;
            int node = node0 + n;
            float4 v = make_float4(0.f, 0.f, 0.f, 0.f);
            if (node < NN) v = x4[(size_t)node * K4 + ch * KC4 + k4l];
            Xq[i] = v;
        }
        __syncthreads();
        #pragma unroll 4
        for (int k4 = 0; k4 < KC4; ++k4) {
            float4 xv[4], wv[4];
            #pragma unroll
            for (int i = 0; i < 4; ++i) xv[i] = Xq[(nb + i) * KC4 + k4];
            int kbase = (ch * KC4 + k4) * 4;
            #pragma unroll
            for (int kk = 0; kk < 4; ++kk) wv[kk] = Wq[(kbase + kk) * MG + mg];
            #pragma unroll
            for (int i = 0; i < 4; ++i) {
                const float* xf = (const float*)&xv[i];
                #pragma unroll
                for (int kk = 0; kk < 4; ++kk) {
                    const float* wf = (const float*)&wv[kk];
                    float xs = xf[kk];
                    acc[i][0] = fmaf(xs, wf[0], acc[i][0]);
                    acc[i][1] = fmaf(xs, wf[1], acc[i][1]);
                    acc[i][2] = fmaf(xs, wf[2], acc[i][2]);
                    acc[i][3] = fmaf(xs, wf[3], acc[i][3]);
                }
            }
        }
    }

    constexpr int TPH = C / 4;               // threads covering one head's cols
    int head = mg / TPH;
    int c0   = (mg % TPH) * 4;
    float ad[4], as_[4];
    #pragma unroll
    for (int j = 0; j < 4; ++j) {
        ad[j]  = att[head * 2 * C + c0 + j];
        as_[j] = att[head * 2 * C + C + c0 + j];
    }
    #pragma unroll
    for (int i = 0; i < 4; ++i) {
        int node = node0 + nb + i;
        if (node < NN) {
            unsigned short us[4];
            #pragma unroll
            for (int j = 0; j < 4; ++j) {
                __hip_bfloat16 b = __float2bfloat16(acc[i][j]);
                us[j] = *(unsigned short*)&b;
            }
            uint2 pk;
            pk.x = (unsigned)us[0] | ((unsigned)us[1] << 16);
            pk.y = (unsigned)us[2] | ((unsigned)us[3] << 16);
            *(uint2*)(Rb + (size_t)node * RSU + 8 + 2 * mg) = pk;
        }
        float pd = acc[i][0]*ad[0]  + acc[i][1]*ad[1]  + acc[i][2]*ad[2]  + acc[i][3]*ad[3];
        float ps = acc[i][0]*as_[0] + acc[i][1]*as_[1] + acc[i][2]*as_[2] + acc[i][3]*as_[3];
        #pragma unroll
        for (int off = 1; off < TPH; off <<= 1) {
            pd += __shfl_xor(pd, off, 64);
            ps += __shfl_xor(ps, off, 64);
        }
        if ((mg % TPH) == 0 && node < NN) {
            sdst[node * H + head] = pd;
            ((float*)(Rb + (size_t)node * RSU))[head] = ps;
        }
    }
}

// ---------------- Aggregation: one wave per node, U-edge masked loop ----------

template<int CT, int H, int U, int RSU, bool ELU_OUT>
__global__ __launch_bounds__(256) void agg_k(const int* __restrict__ rowptr, const int* __restrict__ col,
                      const float* __restrict__ sdst, const unsigned* __restrict__ Rb,
                      const float* __restrict__ bias, float* __restrict__ output) {
    constexpr int C    = CT / H;         // channels per head
    constexpr int CP   = CT / 2;         // lanes covering one packed row
    constexpr int G    = 64 / CP;        // edge slots per gather instruction
    constexpr int NL   = U / G;          // row gathers in flight per lane
    constexpr int EPEL = (U * H >= 64) ? (U * H) / 64 : 1;   // edges per exp lane
    static_assert(EPEL == 1 || EPEL == 2, "mapping");

    int lane = threadIdx.x & 63;
    int node = blockIdx.x * (blockDim.x >> 6) + (threadIdx.x >> 6);
    if (node >= NN) return;

    int cp = lane % CP;                  // channel pair {2cp, 2cp+1}
    int pp = lane / CP;                  // gather slot parity (0..G-1)
    int hh = (2 * cp) / C;               // head of these channels
    int eh = lane % H;                   // exp-lane head
    int gb = lane / H;                   // exp-lane base edge slot

    float sd = (lane < U * H) ? sdst[node * H + eh] : 0.f;

    int start = rowptr[node], end = rowptr[node + 1];
    int total = end + 1;                 // + virtual self-loop at index 'end'
    float2 acc = make_float2(0.f, 0.f);
    float dsum = 0.f;

    for (int j = start; j < total; j += U) {
        // cooperative col load: lane l<U covers list index j+l (clamped to node)
        int cv = node;
        {
            int idx = j + lane;
            if (lane < U && idx < end) cv = col[idx];
        }
        // exp lanes
        float e1 = 0.f, e2 = 0.f;
        if (EPEL == 2) {
            int b1 = __shfl(cv, gb, 64);
            int b2 = __shfl(cv, gb + U / 2, 64);
            float s1 = ((const float*)(Rb + (size_t)b1 * RSU))[eh];
            float s2 = ((const float*)(Rb + (size_t)b2 * RSU))[eh];
            float a1 = sd + s1; a1 = (a1 >= 0.f) ? a1 : 0.2f * a1;
            float a2 = sd + s2; a2 = (a2 >= 0.f) ? a2 : 0.2f * a2;
            if (j + gb < total)          e1 = __expf(a1);
            if (j + gb + U / 2 < total)  e2 = __expf(a2);
            dsum += e1 + e2;
        } else {
            if (lane < U * H) {
                float s1 = ((const float*)(Rb + (size_t)cv * RSU))[eh];
                float a1 = sd + s1; a1 = (a1 >= 0.f) ? a1 : 0.2f * a1;
                if (j + gb < total) e1 = __expf(a1);
                dsum += e1;
            }
        }
        // row gathers (independent, all issued before use)
        unsigned hv[NL];
        #pragma unroll
        for (int t = 0; t < NL; ++t) {
            int se = __shfl(cv, t * G + pp, 64);
            hv[t] = Rb[(size_t)se * RSU + 8 + cp];
        }
        #pragma unroll
        for (int t = 0; t < NL; ++t) {
            int eidx = t * G + pp;
            float ex;
            if (EPEL == 2)
                ex = __shfl((t < NL / 2) ? e1 : e2, (eidx & (U / 2 - 1)) * H + hh, 64);
            else
                ex = __shfl(e1, eidx * H + hh, 64);
            float hx = __uint_as_float(hv[t] << 16);
            float hy = __uint_as_float(hv[t] & 0xffff0000u);
            acc.x = fmaf(ex, hx, acc.x);
            acc.y = fmaf(ex, hy, acc.y);
        }
    }
    // reduce dsum over edge-slot lanes (masked lanes contribute 0)
    #pragma unroll
    for (int off = H; off < 64; off <<= 1) dsum += __shfl_xor(dsum, off, 64);
    float den = __shfl(dsum, hh, 64);    // lane 'hh' holds head hh's full sum
    // reduce acc over gather-slot parities
    #pragma unroll
    for (int off = CP; off < 64; off <<= 1) {
        acc.x += __shfl_xor(acc.x, off, 64);
        acc.y += __shfl_xor(acc.y, off, 64);
    }
    if (lane < CP) {
        float inv = 1.f / den;
        float vx = acc.x * inv + bias[2 * cp];
        float vy = acc.y * inv + bias[2 * cp + 1];
        if (ELU_OUT) {
            vx = (vx > 0.f) ? vx : expm1f(vx);       // ELU(alpha=1)
            vy = (vy > 0.f) ? vy : expm1f(vy);
        }
        ((float2*)output)[(size_t)node * CP + cp] = make_float2(vx, vy);
    }
}

// ---------------- launch ----------------

extern "C" void kernel_launch(void* const* d_in, const int* in_sizes, int n_in,
                              void* d_out, int out_size, void* d_ws, size_t ws_size,
                              hipStream_t stream) {
    const float* x    = (const float*)d_in[0];
    const int*   ei   = (const int*)d_in[1];
    const float* W1   = (const float*)d_in[2];
    const float* att1 = (const float*)d_in[3];
    const float* b1   = (const float*)d_in[4];
    const float* W2   = (const float*)d_in[5];
    const float* att2 = (const float*)d_in[6];
    const float* b2   = (const float*)d_in[7];
    const float* W3   = (const float*)d_in[8];
    const float* att3 = (const float*)d_in[9];
    const float* b3   = (const float*)d_in[10];
    float* out = (float*)d_out;

    char* p = (char*)d_ws;
    auto alloc = [&](size_t bytes) -> void* {
        void* r = (void*)p;
        p += (bytes + 255) & ~(size_t)255;
        return r;
    };
    int*   rowptr   = (int*)alloc((NN + 1) * sizeof(int));
    int*   deg      = (int*)alloc(NN * sizeof(int));
    int*   degR     = (int*)alloc((size_t)RPL * NN * sizeof(int));
    int*   partials = (int*)alloc(NB_SCAN * sizeof(int));
    int*   col      = (int*)alloc(EE * sizeof(int));
    int*   rank     = (int*)alloc(EE * sizeof(int));
    float* sdst     = (float*)alloc((size_t)NN * 8 * sizeof(float));
    unsigned* Rb    = (unsigned*)alloc((size_t)NN * 48 * sizeof(unsigned));
    float* Fb       = (float*)alloc((size_t)NN * 64 * sizeof(float));

    // --- CSR build (dst-grouped, original non-self edges only) ---
    zero_int<<<(RPL * NN + 255) / 256, 256, 0, stream>>>(degR, RPL * NN);
    hist_rank_k<<<(EE + HB - 1) / HB, 256, 0, stream>>>(ei, degR, rank);
    combine_k<<<(NN + 255) / 256, 256, 0, stream>>>(degR, deg);
    sum_blocks<<<NB_SCAN, 256, 0, stream>>>(deg, partials);
    scan_partials<<<1, 128, 0, stream>>>(partials);
    scan_final<<<NB_SCAN, 256, 0, stream>>>(deg, partials, rowptr, degR);
    scatter2_k<<<CB * NR, 256, 0, stream>>>(ei, rank, degR, col);

    // --- Layer 1: x[N,128] -> h[N,64]; H=8, C=8; ELU out -> Fb ---
    gemm_tile<128, 64, 8, 64, 48><<<(NN + 63) / 64, 256, 0, stream>>>(x, W1, att1, Rb, sdst);
    agg_k<64, 8, 16, 48, true><<<(NN + 3) / 4, 256, 0, stream>>>(rowptr, col, sdst, Rb, b1, Fb);

    // --- Layer 2: Fb[N,64] -> h[N,64]; H=8, C=8; ELU out -> Fb ---
    gemm_tile<64, 64, 8, 64, 48><<<(NN + 63) / 64, 256, 0, stream>>>(Fb, W2, att2, Rb, sdst);
    agg_k<64, 8, 16, 48, true><<<(NN + 3) / 4, 256, 0, stream>>>(rowptr, col, sdst, Rb, b2, Fb);

    // --- Layer 3: Fb[N,64] -> h[N,32]; H=1, C=32; no ELU, f32 out -> d_out ---
    gemm_tile<64, 32, 1, 128, 32><<<(NN + 127) / 128, 256, 0, stream>>>(Fb, W3, att3, Rb, sdst);
    agg_k<32, 1, 32, 32, false><<<(NN + 3) / 4, 256, 0, stream>>>(rowptr, col, sdst, Rb, b3, out);
}

// Round 11
// 429.072 us; speedup vs baseline: 1.0754x; 1.0754x over previous
//
#include <hip/hip_runtime.h>
#include <hip/hip_bf16.h>

#define NN 100000
#define EE 1600000

constexpr int SCAN_BLK = 1024;                       // elements per scan block (256 thr * 4)
constexpr int NB_SCAN  = (NN + SCAN_BLK - 1) / SCAN_BLK;  // 98

// LDS counting-sort CSR build: 8 dst-ranges x 32 edge-chunks
constexpr int NR2 = 8;              // dst ranges (12500 nodes -> 50 KB LDS histogram)
constexpr int RSZ = NN / NR2;       // 12500
constexpr int CH  = 32;             // edge chunks
constexpr int CSZ = EE / CH;        // 50000 edges per chunk

// ---------------- CSR build (no global atomics) ----------------

// Phase A: block (c,r) histograms its chunk's in-range dsts in LDS, writes
// CntG[c][node] coalesced.
__global__ __launch_bounds__(256) void histL_k(const int* __restrict__ ei,
                                               int* __restrict__ CntG) {
    __shared__ int cnt[RSZ];
    int r = blockIdx.x % NR2, c = blockIdx.x / NR2;
    int lo = r * RSZ;
    for (int t = threadIdx.x; t < RSZ; t += 256) cnt[t] = 0;
    __syncthreads();
    const int* __restrict__ dstp = ei + EE;
    int base = c * CSZ;
    int tid = threadIdx.x;
    for (int ii = 0; ii < CSZ; ii += 1024) {
        int d[4], s[4];
        #pragma unroll
        for (int k = 0; k < 4; ++k) {
            int off = ii + tid + k * 256;
            bool v = off < CSZ;
            d[k] = v ? dstp[base + off] : -1;
            s[k] = v ? ei[base + off]   : -1;
        }
        #pragma unroll
        for (int k = 0; k < 4; ++k) {
            int dl = d[k] - lo;
            if (dl >= 0 && dl < RSZ && s[k] != d[k]) atomicAdd(&cnt[dl], 1);
        }
    }
    __syncthreads();
    for (int t = threadIdx.x; t < RSZ; t += 256)
        CntG[(size_t)c * NN + lo + t] = cnt[t];
}

// Phase B: per node, exclusive prefix over chunks; total -> deg.
__global__ void combineL_k(int* __restrict__ CntG, int* __restrict__ deg) {
    int d = blockIdx.x * 256 + threadIdx.x;
    if (d < NN) {
        int run = 0;
        #pragma unroll 8
        for (int c = 0; c < CH; ++c) {
            int v = CntG[(size_t)c * NN + d];
            CntG[(size_t)c * NN + d] = run;
            run += v;
        }
        deg[d] = run;
    }
}

__global__ void sum_blocks(const int* __restrict__ deg, int* __restrict__ partials) {
    __shared__ int sh[256];
    int t = threadIdx.x;
    int base = blockIdx.x * SCAN_BLK + t * 4;
    int s = 0;
    #pragma unroll
    for (int k = 0; k < 4; ++k) { int i = base + k; if (i < NN) s += deg[i]; }
    sh[t] = s; __syncthreads();
    for (int off = 128; off > 0; off >>= 1) {
        if (t < off) sh[t] += sh[t + off];
        __syncthreads();
    }
    if (t == 0) partials[blockIdx.x] = sh[0];
}

__global__ void scan_partials(int* __restrict__ partials) {
    __shared__ int sh[128];
    int t = threadIdx.x;
    int v = (t < NB_SCAN) ? partials[t] : 0;
    sh[t] = v;
    __syncthreads();
    for (int off = 1; off < 128; off <<= 1) {
        int tmp = (t >= off) ? sh[t - off] : 0;
        __syncthreads();
        sh[t] += tmp;
        __syncthreads();
    }
    if (t < NB_SCAN) partials[t] = sh[t] - v;   // exclusive prefix
}

__global__ void scan_final(const int* __restrict__ deg, const int* __restrict__ partials,
                           int* __restrict__ rowptr) {
    __shared__ int sh[256];
    int t = threadIdx.x;
    int base = blockIdx.x * SCAN_BLK + t * 4;
    int v[4]; int s = 0;
    #pragma unroll
    for (int k = 0; k < 4; ++k) { int i = base + k; v[k] = (i < NN) ? deg[i] : 0; s += v[k]; }
    sh[t] = s; __syncthreads();
    for (int off = 1; off < 256; off <<= 1) {
        int tmp = (t >= off) ? sh[t - off] : 0;
        __syncthreads();
        sh[t] += tmp;
        __syncthreads();
    }
    int pref = partials[blockIdx.x] + sh[t] - s;
    #pragma unroll
    for (int k = 0; k < 4; ++k) {
        int i = base + k;
        if (i < NN) {
            rowptr[i] = pref; pref += v[k];
            if (i == NN - 1) rowptr[NN] = pref;
        }
    }
}

// Phase C: LDS cursors seeded from rowptr + chunk prefix; LDS atomic rank,
// random col write. No global atomics.
__global__ __launch_bounds__(256) void scatterL_k(const int* __restrict__ ei,
                                                  const int* __restrict__ CntG,
                                                  const int* __restrict__ rowptr,
                                                  int* __restrict__ col) {
    __shared__ int cur[RSZ];
    int r = blockIdx.x % NR2, c = blockIdx.x / NR2;
    int lo = r * RSZ;
    for (int t = threadIdx.x; t < RSZ; t += 256)
        cur[t] = rowptr[lo + t] + CntG[(size_t)c * NN + lo + t];
    __syncthreads();
    const int* __restrict__ dstp = ei + EE;
    int base = c * CSZ;
    int tid = threadIdx.x;
    for (int ii = 0; ii < CSZ; ii += 1024) {
        int d[4], s[4];
        #pragma unroll
        for (int k = 0; k < 4; ++k) {
            int off = ii + tid + k * 256;
            bool v = off < CSZ;
            d[k] = v ? dstp[base + off] : -1;
            s[k] = v ? ei[base + off]   : -1;
        }
        #pragma unroll
        for (int k = 0; k < 4; ++k) {
            int dl = d[k] - lo;
            if (dl >= 0 && dl < RSZ && s[k] != d[k]) {
                int p = atomicAdd(&cur[dl], 1);
                col[p] = s[k];
            }
        }
    }
}

// ---------------- GEMM (h = x @ W) + per-node record ----------------
// Register-blocked 4x4 per thread. Epilogue writes an interleaved per-node
// record into Rb (stride RSU uints): [0..H) = ssrc (f32), [8..8+M/2) = h (bf16
// packed 2/uint). sdst stays a separate f32 array (only read for own node).

template<int K, int M, int H, int NPB, int RSU>
__global__ __launch_bounds__(256) void gemm_tile(const float* __restrict__ xin,
                          const float* __restrict__ W,
                          const float* __restrict__ att,
                          unsigned* __restrict__ Rb,
                          float* __restrict__ sdst) {
    constexpr int C   = M / H;
    constexpr int MG  = M / 4;               // col-groups (4 cols per thread)
    constexpr int NG  = NPB / 4;
    static_assert(MG * NG == 256, "tile mismatch");
    constexpr int K4  = K / 4;
    constexpr int KC4 = (K4 > 16) ? 16 : K4;
    constexpr int NCH = K4 / KC4;

    __shared__ float4 Wq[K * MG];
    __shared__ float4 Xq[NPB * KC4];

    int tid = threadIdx.x;
    const float4* W4 = (const float4*)W;
    for (int i = tid; i < K * MG; i += 256) Wq[i] = W4[i];

    int node0 = blockIdx.x * NPB;
    const float4* x4 = (const float4*)xin;

    int mg = tid % MG, ng = tid / MG;
    int nb = ng * 4;
    float acc[4][4];
    #pragma unroll
    for (int i = 0; i < 4; ++i)
        #pragma unroll
        for (int j = 0; j < 4; ++j) acc[i][j] = 0.f;

    for (int ch = 0; ch < NCH; ++ch) {
        __syncthreads();
        for (int i = tid; i < NPB * KC4; i += 256) {
            int n = i / KC4, k4l = i % KC4;
            int node = node0 + n;
            float4 v = make_float4(0.f, 0.f, 0.f, 0.f);
            if (node < NN) v = x4[(size_t)node * K4 + ch * KC4 + k4l];
            Xq[i] = v;
        }
        __syncthreads();
        #pragma unroll 4
        for (int k4 = 0; k4 < KC4; ++k4) {
            float4 xv[4], wv[4];
            #pragma unroll
            for (int i = 0; i < 4; ++i) xv[i] = Xq[(nb + i) * KC4 + k4];
            int kbase = (ch * KC4 + k4) * 4;
            #pragma unroll
            for (int kk = 0; kk < 4; ++kk) wv[kk] = Wq[(kbase + kk) * MG + mg];
            #pragma unroll
            for (int i = 0; i < 4; ++i) {
                const float* xf = (const float*)&xv[i];
                #pragma unroll
                for (int kk = 0; kk < 4; ++kk) {
                    const float* wf = (const float*)&wv[kk];
                    float xs = xf[kk];
                    acc[i][0] = fmaf(xs, wf[0], acc[i][0]);
                    acc[i][1] = fmaf(xs, wf[1], acc[i][1]);
                    acc[i][2] = fmaf(xs, wf[2], acc[i][2]);
                    acc[i][3] = fmaf(xs, wf[3], acc[i][3]);
                }
            }
        }
    }

    constexpr int TPH = C / 4;               // threads covering one head's cols
    int head = mg / TPH;
    int c0   = (mg % TPH) * 4;
    float ad[4], as_[4];
    #pragma unroll
    for (int j = 0; j < 4; ++j) {
        ad[j]  = att[head * 2 * C + c0 + j];
        as_[j] = att[head * 2 * C + C + c0 + j];
    }
    #pragma unroll
    for (int i = 0; i < 4; ++i) {
        int node = node0 + nb + i;
        if (node < NN) {
            unsigned short us[4];
            #pragma unroll
            for (int j = 0; j < 4; ++j) {
                __hip_bfloat16 b = __float2bfloat16(acc[i][j]);
                us[j] = *(unsigned short*)&b;
            }
            uint2 pk;
            pk.x = (unsigned)us[0] | ((unsigned)us[1] << 16);
            pk.y = (unsigned)us[2] | ((unsigned)us[3] << 16);
            *(uint2*)(Rb + (size_t)node * RSU + 8 + 2 * mg) = pk;
        }
        float pd = acc[i][0]*ad[0]  + acc[i][1]*ad[1]  + acc[i][2]*ad[2]  + acc[i][3]*ad[3];
        float ps = acc[i][0]*as_[0] + acc[i][1]*as_[1] + acc[i][2]*as_[2] + acc[i][3]*as_[3];
        #pragma unroll
        for (int off = 1; off < TPH; off <<= 1) {
            pd += __shfl_xor(pd, off, 64);
            ps += __shfl_xor(ps, off, 64);
        }
        if ((mg % TPH) == 0 && node < NN) {
            sdst[node * H + head] = pd;
            ((float*)(Rb + (size_t)node * RSU))[head] = ps;
        }
    }
}

// ---------------- Aggregation: one wave per node, U-edge masked loop ----------

template<int CT, int H, int U, int RSU, bool ELU_OUT>
__global__ __launch_bounds__(256) void agg_k(const int* __restrict__ rowptr, const int* __restrict__ col,
                      const float* __restrict__ sdst, const unsigned* __restrict__ Rb,
                      const float* __restrict__ bias, float* __restrict__ output) {
    constexpr int C    = CT / H;         // channels per head
    constexpr int CP   = CT / 2;         // lanes covering one packed row
    constexpr int G    = 64 / CP;        // edge slots per gather instruction
    constexpr int NL   = U / G;          // row gathers in flight per lane
    constexpr int EPEL = (U * H >= 64) ? (U * H) / 64 : 1;   // edges per exp lane
    static_assert(EPEL == 1 || EPEL == 2, "mapping");

    int lane = threadIdx.x & 63;
    int node = blockIdx.x * (blockDim.x >> 6) + (threadIdx.x >> 6);
    if (node >= NN) return;

    int cp = lane % CP;                  // channel pair {2cp, 2cp+1}
    int pp = lane / CP;                  // gather slot parity (0..G-1)
    int hh = (2 * cp) / C;               // head of these channels
    int eh = lane % H;                   // exp-lane head
    int gb = lane / H;                   // exp-lane base edge slot

    float sd = (lane < U * H) ? sdst[node * H + eh] : 0.f;

    int start = rowptr[node], end = rowptr[node + 1];
    int total = end + 1;                 // + virtual self-loop at index 'end'
    float2 acc = make_float2(0.f, 0.f);
    float dsum = 0.f;

    for (int j = start; j < total; j += U) {
        // cooperative col load: lane l<U covers list index j+l (clamped to node)
        int cv = node;
        {
            int idx = j + lane;
            if (lane < U && idx < end) cv = col[idx];
        }
        // exp lanes
        float e1 = 0.f, e2 = 0.f;
        if (EPEL == 2) {
            int b1 = __shfl(cv, gb, 64);
            int b2 = __shfl(cv, gb + U / 2, 64);
            float s1 = ((const float*)(Rb + (size_t)b1 * RSU))[eh];
            float s2 = ((const float*)(Rb + (size_t)b2 * RSU))[eh];
            float a1 = sd + s1; a1 = (a1 >= 0.f) ? a1 : 0.2f * a1;
            float a2 = sd + s2; a2 = (a2 >= 0.f) ? a2 : 0.2f * a2;
            if (j + gb < total)          e1 = __expf(a1);
            if (j + gb + U / 2 < total)  e2 = __expf(a2);
            dsum += e1 + e2;
        } else {
            if (lane < U * H) {
                float s1 = ((const float*)(Rb + (size_t)cv * RSU))[eh];
                float a1 = sd + s1; a1 = (a1 >= 0.f) ? a1 : 0.2f * a1;
                if (j + gb < total) e1 = __expf(a1);
                dsum += e1;
            }
        }
        // row gathers (independent, all issued before use)
        unsigned hv[NL];
        #pragma unroll
        for (int t = 0; t < NL; ++t) {
            int se = __shfl(cv, t * G + pp, 64);
            hv[t] = Rb[(size_t)se * RSU + 8 + cp];
        }
        #pragma unroll
        for (int t = 0; t < NL; ++t) {
            int eidx = t * G + pp;
            float ex;
            if (EPEL == 2)
                ex = __shfl((t < NL / 2) ? e1 : e2, (eidx & (U / 2 - 1)) * H + hh, 64);
            else
                ex = __shfl(e1, eidx * H + hh, 64);
            float hx = __uint_as_float(hv[t] << 16);
            float hy = __uint_as_float(hv[t] & 0xffff0000u);
            acc.x = fmaf(ex, hx, acc.x);
            acc.y = fmaf(ex, hy, acc.y);
        }
    }
    // reduce dsum over edge-slot lanes (masked lanes contribute 0)
    #pragma unroll
    for (int off = H; off < 64; off <<= 1) dsum += __shfl_xor(dsum, off, 64);
    float den = __shfl(dsum, hh, 64);    // lane 'hh' holds head hh's full sum
    // reduce acc over gather-slot parities
    #pragma unroll
    for (int off = CP; off < 64; off <<= 1) {
        acc.x += __shfl_xor(acc.x, off, 64);
        acc.y += __shfl_xor(acc.y, off, 64);
    }
    if (lane < CP) {
        float inv = 1.f / den;
        float vx = acc.x * inv + bias[2 * cp];
        float vy = acc.y * inv + bias[2 * cp + 1];
        if (ELU_OUT) {
            vx = (vx > 0.f) ? vx : expm1f(vx);       // ELU(alpha=1)
            vy = (vy > 0.f) ? vy : expm1f(vy);
        }
        ((float2*)output)[(size_t)node * CP + cp] = make_float2(vx, vy);
    }
}

// ---------------- launch ----------------

extern "C" void kernel_launch(void* const* d_in, const int* in_sizes, int n_in,
                              void* d_out, int out_size, void* d_ws, size_t ws_size,
                              hipStream_t stream) {
    const float* x    = (const float*)d_in[0];
    const int*   ei   = (const int*)d_in[1];
    const float* W1   = (const float*)d_in[2];
    const float* att1 = (const float*)d_in[3];
    const float* b1   = (const float*)d_in[4];
    const float* W2   = (const float*)d_in[5];
    const float* att2 = (const float*)d_in[6];
    const float* b2   = (const float*)d_in[7];
    const float* W3   = (const float*)d_in[8];
    const float* att3 = (const float*)d_in[9];
    const float* b3   = (const float*)d_in[10];
    float* out = (float*)d_out;

    char* p = (char*)d_ws;
    auto alloc = [&](size_t bytes) -> void* {
        void* r = (void*)p;
        p += (bytes + 255) & ~(size_t)255;
        return r;
    };
    int*   rowptr   = (int*)alloc((NN + 1) * sizeof(int));
    int*   deg      = (int*)alloc(NN * sizeof(int));
    int*   CntG     = (int*)alloc((size_t)CH * NN * sizeof(int));
    int*   partials = (int*)alloc(NB_SCAN * sizeof(int));
    int*   col      = (int*)alloc(EE * sizeof(int));
    float* sdst     = (float*)alloc((size_t)NN * 8 * sizeof(float));
    unsigned* Rb    = (unsigned*)alloc((size_t)NN * 48 * sizeof(unsigned));
    float* Fb       = (float*)alloc((size_t)NN * 64 * sizeof(float));

    // --- CSR build (dst-grouped, original non-self edges only; no global atomics) ---
    histL_k<<<CH * NR2, 256, 0, stream>>>(ei, CntG);
    combineL_k<<<(NN + 255) / 256, 256, 0, stream>>>(CntG, deg);
    sum_blocks<<<NB_SCAN, 256, 0, stream>>>(deg, partials);
    scan_partials<<<1, 128, 0, stream>>>(partials);
    scan_final<<<NB_SCAN, 256, 0, stream>>>(deg, partials, rowptr);
    scatterL_k<<<CH * NR2, 256, 0, stream>>>(ei, CntG, rowptr, col);

    // --- Layer 1: x[N,128] -> h[N,64]; H=8, C=8; ELU out -> Fb ---
    gemm_tile<128, 64, 8, 64, 48><<<(NN + 63) / 64, 256, 0, stream>>>(x, W1, att1, Rb, sdst);
    agg_k<64, 8, 16, 48, true><<<(NN + 3) / 4, 256, 0, stream>>>(rowptr, col, sdst, Rb, b1, Fb);

    // --- Layer 2: Fb[N,64] -> h[N,64]; H=8, C=8; ELU out -> Fb ---
    gemm_tile<64, 64, 8, 64, 48><<<(NN + 63) / 64, 256, 0, stream>>>(Fb, W2, att2, Rb, sdst);
    agg_k<64, 8, 16, 48, true><<<(NN + 3) / 4, 256, 0, stream>>>(rowptr, col, sdst, Rb, b2, Fb);

    // --- Layer 3: Fb[N,64] -> h[N,32]; H=1, C=32; no ELU, f32 out -> d_out ---
    gemm_tile<64, 32, 1, 128, 32><<<(NN + 127) / 128, 256, 0, stream>>>(Fb, W3, att3, Rb, sdst);
    agg_k<32, 1, 32, 32, false><<<(NN + 3) / 4, 256, 0, stream>>>(rowptr, col, sdst, Rb, b3, out);
}

// Round 12
// 425.290 us; speedup vs baseline: 1.0850x; 1.0089x over previous
//
#include <hip/hip_runtime.h>
#include <hip/hip_bf16.h>

#define NN 100000
#define EE 1600000

constexpr int SCAN_BLK = 1024;                       // elements per scan block (256 thr * 4)
constexpr int NB_SCAN  = (NN + SCAN_BLK - 1) / SCAN_BLK;  // 98

// LDS counting-sort CSR build: 8 dst-ranges x 32 edge-chunks
constexpr int NR2 = 8;              // dst ranges (12500 nodes -> 50 KB LDS histogram)
constexpr int RSZ = NN / NR2;       // 12500
constexpr int CH  = 32;             // edge chunks
constexpr int CSZ = EE / CH;        // 50000 edges per chunk

// ---------------- CSR build (no global atomics) ----------------

__global__ __launch_bounds__(256) void histL_k(const int* __restrict__ ei,
                                               int* __restrict__ CntG) {
    __shared__ int cnt[RSZ];
    int r = blockIdx.x % NR2, c = blockIdx.x / NR2;
    int lo = r * RSZ;
    for (int t = threadIdx.x; t < RSZ; t += 256) cnt[t] = 0;
    __syncthreads();
    const int* __restrict__ dstp = ei + EE;
    int base = c * CSZ;
    int tid = threadIdx.x;
    for (int ii = 0; ii < CSZ; ii += 1024) {
        int d[4], s[4];
        #pragma unroll
        for (int k = 0; k < 4; ++k) {
            int off = ii + tid + k * 256;
            bool v = off < CSZ;
            d[k] = v ? dstp[base + off] : -1;
            s[k] = v ? ei[base + off]   : -1;
        }
        #pragma unroll
        for (int k = 0; k < 4; ++k) {
            int dl = d[k] - lo;
            if (dl >= 0 && dl < RSZ && s[k] != d[k]) atomicAdd(&cnt[dl], 1);
        }
    }
    __syncthreads();
    for (int t = threadIdx.x; t < RSZ; t += 256)
        CntG[(size_t)c * NN + lo + t] = cnt[t];
}

__global__ void combineL_k(int* __restrict__ CntG, int* __restrict__ deg) {
    int d = blockIdx.x * 256 + threadIdx.x;
    if (d < NN) {
        int run = 0;
        #pragma unroll 8
        for (int c = 0; c < CH; ++c) {
            int v = CntG[(size_t)c * NN + d];
            CntG[(size_t)c * NN + d] = run;
            run += v;
        }
        deg[d] = run;
    }
}

__global__ void sum_blocks(const int* __restrict__ deg, int* __restrict__ partials) {
    __shared__ int sh[256];
    int t = threadIdx.x;
    int base = blockIdx.x * SCAN_BLK + t * 4;
    int s = 0;
    #pragma unroll
    for (int k = 0; k < 4; ++k) { int i = base + k; if (i < NN) s += deg[i]; }
    sh[t] = s; __syncthreads();
    for (int off = 128; off > 0; off >>= 1) {
        if (t < off) sh[t] += sh[t + off];
        __syncthreads();
    }
    if (t == 0) partials[blockIdx.x] = sh[0];
}

__global__ void scan_partials(int* __restrict__ partials) {
    __shared__ int sh[128];
    int t = threadIdx.x;
    int v = (t < NB_SCAN) ? partials[t] : 0;
    sh[t] = v;
    __syncthreads();
    for (int off = 1; off < 128; off <<= 1) {
        int tmp = (t >= off) ? sh[t - off] : 0;
        __syncthreads();
        sh[t] += tmp;
        __syncthreads();
    }
    if (t < NB_SCAN) partials[t] = sh[t] - v;   // exclusive prefix
}

__global__ void scan_final(const int* __restrict__ deg, const int* __restrict__ partials,
                           int* __restrict__ rowptr) {
    __shared__ int sh[256];
    int t = threadIdx.x;
    int base = blockIdx.x * SCAN_BLK + t * 4;
    int v[4]; int s = 0;
    #pragma unroll
    for (int k = 0; k < 4; ++k) { int i = base + k; v[k] = (i < NN) ? deg[i] : 0; s += v[k]; }
    sh[t] = s; __syncthreads();
    for (int off = 1; off < 256; off <<= 1) {
        int tmp = (t >= off) ? sh[t - off] : 0;
        __syncthreads();
        sh[t] += tmp;
        __syncthreads();
    }
    int pref = partials[blockIdx.x] + sh[t] - s;
    #pragma unroll
    for (int k = 0; k < 4; ++k) {
        int i = base + k;
        if (i < NN) {
            rowptr[i] = pref; pref += v[k];
            if (i == NN - 1) rowptr[NN] = pref;
        }
    }
}

__global__ __launch_bounds__(256) void scatterL_k(const int* __restrict__ ei,
                                                  const int* __restrict__ CntG,
                                                  const int* __restrict__ rowptr,
                                                  int* __restrict__ col) {
    __shared__ int cur[RSZ];
    int r = blockIdx.x % NR2, c = blockIdx.x / NR2;
    int lo = r * RSZ;
    for (int t = threadIdx.x; t < RSZ; t += 256)
        cur[t] = rowptr[lo + t] + CntG[(size_t)c * NN + lo + t];
    __syncthreads();
    const int* __restrict__ dstp = ei + EE;
    int base = c * CSZ;
    int tid = threadIdx.x;
    for (int ii = 0; ii < CSZ; ii += 1024) {
        int d[4], s[4];
        #pragma unroll
        for (int k = 0; k < 4; ++k) {
            int off = ii + tid + k * 256;
            bool v = off < CSZ;
            d[k] = v ? dstp[base + off] : -1;
            s[k] = v ? ei[base + off]   : -1;
        }
        #pragma unroll
        for (int k = 0; k < 4; ++k) {
            int dl = d[k] - lo;
            if (dl >= 0 && dl < RSZ && s[k] != d[k]) {
                int p = atomicAdd(&cur[dl], 1);
                col[p] = s[k];
            }
        }
    }
}

// ---------------- GEMM (h = x @ W) + per-node attention arrays ----------------
// Register-blocked 4x4 per thread. Epilogue writes:
//   Hbf  [NN * M/4] uint2 : h packed bf16, 4 ch/uint2, pow2 row stride (2 lines)
//   ssrcA[NN * H]   f32   : per-(node,head) source score (compact, 3.2 MB)
//   sdst [NN * H]   f32   : per-(node,head) dest score

template<int K, int M, int H, int NPB>
__global__ __launch_bounds__(256) void gemm_tile(const float* __restrict__ xin,
                          const float* __restrict__ W,
                          const float* __restrict__ att,
                          uint2* __restrict__ Hbf,
                          float* __restrict__ ssrcA,
                          float* __restrict__ sdst) {
    constexpr int C   = M / H;
    constexpr int MG  = M / 4;               // col-groups (4 cols per thread)
    constexpr int NG  = NPB / 4;
    static_assert(MG * NG == 256, "tile mismatch");
    constexpr int K4  = K / 4;
    constexpr int KC4 = (K4 > 16) ? 16 : K4;
    constexpr int NCH = K4 / KC4;

    __shared__ float4 Wq[K * MG];
    __shared__ float4 Xq[NPB * KC4];

    int tid = threadIdx.x;
    const float4* W4 = (const float4*)W;
    for (int i = tid; i < K * MG; i += 256) Wq[i] = W4[i];

    int node0 = blockIdx.x * NPB;
    const float4* x4 = (const float4*)xin;

    int mg = tid % MG, ng = tid / MG;
    int nb = ng * 4;
    float acc[4][4];
    #pragma unroll
    for (int i = 0; i < 4; ++i)
        #pragma unroll
        for (int j = 0; j < 4; ++j) acc[i][j] = 0.f;

    for (int ch = 0; ch < NCH; ++ch) {
        __syncthreads();
        for (int i = tid; i < NPB * KC4; i += 256) {
            int n = i / KC4, k4l = i % KC4;
            int node = node0 + n;
            float4 v = make_float4(0.f, 0.f, 0.f, 0.f);
            if (node < NN) v = x4[(size_t)node * K4 + ch * KC4 + k4l];
            Xq[i] = v;
        }
        __syncthreads();
        #pragma unroll 4
        for (int k4 = 0; k4 < KC4; ++k4) {
            float4 xv[4], wv[4];
            #pragma unroll
            for (int i = 0; i < 4; ++i) xv[i] = Xq[(nb + i) * KC4 + k4];
            int kbase = (ch * KC4 + k4) * 4;
            #pragma unroll
            for (int kk = 0; kk < 4; ++kk) wv[kk] = Wq[(kbase + kk) * MG + mg];
            #pragma unroll
            for (int i = 0; i < 4; ++i) {
                const float* xf = (const float*)&xv[i];
                #pragma unroll
                for (int kk = 0; kk < 4; ++kk) {
                    const float* wf = (const float*)&wv[kk];
                    float xs = xf[kk];
                    acc[i][0] = fmaf(xs, wf[0], acc[i][0]);
                    acc[i][1] = fmaf(xs, wf[1], acc[i][1]);
                    acc[i][2] = fmaf(xs, wf[2], acc[i][2]);
                    acc[i][3] = fmaf(xs, wf[3], acc[i][3]);
                }
            }
        }
    }

    constexpr int TPH = C / 4;               // threads covering one head's cols
    int head = mg / TPH;
    int c0   = (mg % TPH) * 4;
    float ad[4], as_[4];
    #pragma unroll
    for (int j = 0; j < 4; ++j) {
        ad[j]  = att[head * 2 * C + c0 + j];
        as_[j] = att[head * 2 * C + C + c0 + j];
    }
    #pragma unroll
    for (int i = 0; i < 4; ++i) {
        int node = node0 + nb + i;
        if (node < NN) {
            unsigned short us[4];
            #pragma unroll
            for (int j = 0; j < 4; ++j) {
                __hip_bfloat16 b = __float2bfloat16(acc[i][j]);
                us[j] = *(unsigned short*)&b;
            }
            uint2 pk;
            pk.x = (unsigned)us[0] | ((unsigned)us[1] << 16);
            pk.y = (unsigned)us[2] | ((unsigned)us[3] << 16);
            Hbf[(size_t)node * MG + mg] = pk;
        }
        float pd = acc[i][0]*ad[0]  + acc[i][1]*ad[1]  + acc[i][2]*ad[2]  + acc[i][3]*ad[3];
        float ps = acc[i][0]*as_[0] + acc[i][1]*as_[1] + acc[i][2]*as_[2] + acc[i][3]*as_[3];
        #pragma unroll
        for (int off = 1; off < TPH; off <<= 1) {
            pd += __shfl_xor(pd, off, 64);
            ps += __shfl_xor(ps, off, 64);
        }
        if ((mg % TPH) == 0 && node < NN) {
            sdst[node * H + head]  = pd;
            ssrcA[node * H + head] = ps;
        }
    }
}

// ---------------- Aggregation: one wave per node, U-edge masked loop ----------
// Hbf: 4 ch per uint2, CP=CT/4 lanes per row, G=64/CP edge slots per gather,
// NL=U/G uint2 gathers in flight. ssrcA compact: each edge's 8 head-reads are
// one contiguous 32 B segment (L2-friendly). All addressing pow2.

template<int CT, int H, int U, bool ELU_OUT>
__global__ __launch_bounds__(256) void agg_k(const int* __restrict__ rowptr, const int* __restrict__ col,
                      const float* __restrict__ sdst, const float* __restrict__ ssrcA,
                      const uint2* __restrict__ Hbf,
                      const float* __restrict__ bias, float* __restrict__ output) {
    constexpr int C    = CT / H;         // channels per head
    constexpr int CP   = CT / 4;         // lanes covering one row (uint2 = 4 ch)
    constexpr int G    = 64 / CP;        // edge slots per gather instruction
    constexpr int NL   = U / G;          // row gathers in flight per lane
    constexpr int EPEL = (U * H >= 64) ? (U * H) / 64 : 1;   // edges per exp lane
    static_assert(EPEL == 1 || EPEL == 2, "mapping");

    int lane = threadIdx.x & 63;
    int node = blockIdx.x * (blockDim.x >> 6) + (threadIdx.x >> 6);
    if (node >= NN) return;

    int cp = lane % CP;                  // channel quad {4cp..4cp+3}
    int pp = lane / CP;                  // gather slot parity (0..G-1)
    int hh = (4 * cp) / C;               // head of these channels (uniform in quad)
    int eh = lane % H;                   // exp-lane head
    int gb = lane / H;                   // exp-lane base edge slot

    float sd = (lane < U * H) ? sdst[node * H + eh] : 0.f;

    int start = rowptr[node], end = rowptr[node + 1];
    int total = end + 1;                 // + virtual self-loop at index 'end'
    float4 acc = make_float4(0.f, 0.f, 0.f, 0.f);
    float dsum = 0.f;

    for (int j = start; j < total; j += U) {
        // cooperative col load: lane l<U covers list index j+l (clamped to node)
        int cv = node;
        {
            int idx = j + lane;
            if (lane < U && idx < end) cv = col[idx];
        }
        // exp lanes
        float e1 = 0.f, e2 = 0.f;
        if (EPEL == 2) {
            int b1 = __shfl(cv, gb, 64);
            int b2 = __shfl(cv, gb + U / 2, 64);
            float s1 = ssrcA[b1 * H + eh];
            float s2 = ssrcA[b2 * H + eh];
            float a1 = sd + s1; a1 = (a1 >= 0.f) ? a1 : 0.2f * a1;
            float a2 = sd + s2; a2 = (a2 >= 0.f) ? a2 : 0.2f * a2;
            if (j + gb < total)          e1 = __expf(a1);
            if (j + gb + U / 2 < total)  e2 = __expf(a2);
            dsum += e1 + e2;
        } else {
            if (lane < U * H) {
                int b1 = __shfl(cv, gb, 64);
                float s1 = ssrcA[b1 * H + eh];
                float a1 = sd + s1; a1 = (a1 >= 0.f) ? a1 : 0.2f * a1;
                if (j + gb < total) e1 = __expf(a1);
                dsum += e1;
            }
        }
        // row gathers (independent, all issued before use)
        uint2 hv[NL];
        #pragma unroll
        for (int t = 0; t < NL; ++t) {
            int se = __shfl(cv, t * G + pp, 64);
            hv[t] = Hbf[(size_t)se * CP + cp];
        }
        #pragma unroll
        for (int t = 0; t < NL; ++t) {
            int eidx = t * G + pp;
            float ex;
            if (EPEL == 2)
                ex = __shfl((t * G + G - 1 < U / 2) ? e1 : e2, (eidx & (U / 2 - 1)) * H + hh, 64);
            else
                ex = __shfl(e1, eidx * H + hh, 64);
            float f0 = __uint_as_float(hv[t].x << 16);
            float f1 = __uint_as_float(hv[t].x & 0xffff0000u);
            float f2 = __uint_as_float(hv[t].y << 16);
            float f3 = __uint_as_float(hv[t].y & 0xffff0000u);
            acc.x = fmaf(ex, f0, acc.x);
            acc.y = fmaf(ex, f1, acc.y);
            acc.z = fmaf(ex, f2, acc.z);
            acc.w = fmaf(ex, f3, acc.w);
        }
    }
    // reduce dsum over edge-slot lanes (masked lanes contribute 0)
    #pragma unroll
    for (int off = H; off < 64; off <<= 1) dsum += __shfl_xor(dsum, off, 64);
    float den = __shfl(dsum, hh, 64);    // lane 'hh' holds head hh's full sum
    // reduce acc over gather-slot parities
    #pragma unroll
    for (int off = CP; off < 64; off <<= 1) {
        acc.x += __shfl_xor(acc.x, off, 64);
        acc.y += __shfl_xor(acc.y, off, 64);
        acc.z += __shfl_xor(acc.z, off, 64);
        acc.w += __shfl_xor(acc.w, off, 64);
    }
    if (lane < CP) {
        float inv = 1.f / den;
        float4 bv = ((const float4*)bias)[cp];
        float4 v;
        v.x = acc.x * inv + bv.x;
        v.y = acc.y * inv + bv.y;
        v.z = acc.z * inv + bv.z;
        v.w = acc.w * inv + bv.w;
        if (ELU_OUT) {
            v.x = (v.x > 0.f) ? v.x : expm1f(v.x);   // ELU(alpha=1)
            v.y = (v.y > 0.f) ? v.y : expm1f(v.y);
            v.z = (v.z > 0.f) ? v.z : expm1f(v.z);
            v.w = (v.w > 0.f) ? v.w : expm1f(v.w);
        }
        ((float4*)output)[(size_t)node * CP + cp] = v;
    }
}

// ---------------- launch ----------------

extern "C" void kernel_launch(void* const* d_in, const int* in_sizes, int n_in,
                              void* d_out, int out_size, void* d_ws, size_t ws_size,
                              hipStream_t stream) {
    const float* x    = (const float*)d_in[0];
    const int*   ei   = (const int*)d_in[1];
    const float* W1   = (const float*)d_in[2];
    const float* att1 = (const float*)d_in[3];
    const float* b1   = (const float*)d_in[4];
    const float* W2   = (const float*)d_in[5];
    const float* att2 = (const float*)d_in[6];
    const float* b2   = (const float*)d_in[7];
    const float* W3   = (const float*)d_in[8];
    const float* att3 = (const float*)d_in[9];
    const float* b3   = (const float*)d_in[10];
    float* out = (float*)d_out;

    char* p = (char*)d_ws;
    auto alloc = [&](size_t bytes) -> void* {
        void* r = (void*)p;
        p += (bytes + 255) & ~(size_t)255;
        return r;
    };
    int*   rowptr   = (int*)alloc((NN + 1) * sizeof(int));
    int*   deg      = (int*)alloc(NN * sizeof(int));
    int*   CntG     = (int*)alloc((size_t)CH * NN * sizeof(int));
    int*   partials = (int*)alloc(NB_SCAN * sizeof(int));
    int*   col      = (int*)alloc(EE * sizeof(int));
    float* sdst     = (float*)alloc((size_t)NN * 8 * sizeof(float));
    float* ssrcA    = (float*)alloc((size_t)NN * 8 * sizeof(float));
    uint2* Hbf      = (uint2*)alloc((size_t)NN * 16 * sizeof(uint2));
    float* Fb       = (float*)alloc((size_t)NN * 64 * sizeof(float));

    // --- CSR build (dst-grouped, original non-self edges only; no global atomics) ---
    histL_k<<<CH * NR2, 256, 0, stream>>>(ei, CntG);
    combineL_k<<<(NN + 255) / 256, 256, 0, stream>>>(CntG, deg);
    sum_blocks<<<NB_SCAN, 256, 0, stream>>>(deg, partials);
    scan_partials<<<1, 128, 0, stream>>>(partials);
    scan_final<<<NB_SCAN, 256, 0, stream>>>(deg, partials, rowptr);
    scatterL_k<<<CH * NR2, 256, 0, stream>>>(ei, CntG, rowptr, col);

    // --- Layer 1: x[N,128] -> h[N,64]; H=8, C=8; ELU out -> Fb ---
    gemm_tile<128, 64, 8, 64><<<(NN + 63) / 64, 256, 0, stream>>>(x, W1, att1, Hbf, ssrcA, sdst);
    agg_k<64, 8, 16, true><<<(NN + 3) / 4, 256, 0, stream>>>(rowptr, col, sdst, ssrcA, Hbf, b1, Fb);

    // --- Layer 2: Fb[N,64] -> h[N,64]; H=8, C=8; ELU out -> Fb ---
    gemm_tile<64, 64, 8, 64><<<(NN + 63) / 64, 256, 0, stream>>>(Fb, W2, att2, Hbf, ssrcA, sdst);
    agg_k<64, 8, 16, true><<<(NN + 3) / 4, 256, 0, stream>>>(rowptr, col, sdst, ssrcA, Hbf, b2, Fb);

    // --- Layer 3: Fb[N,64] -> h[N,32]; H=1, C=32; no ELU, f32 out -> d_out ---
    gemm_tile<64, 32, 1, 128><<<(NN + 127) / 128, 256, 0, stream>>>(Fb, W3, att3, Hbf, ssrcA, sdst);
    agg_k<32, 1, 32, false><<<(NN + 3) / 4, 256, 0, stream>>>(rowptr, col, sdst, ssrcA, Hbf, b3, out);
}